// Round 1
// baseline (35106.250 us; speedup 1.0000x reference)
//
#include <hip/hip_runtime.h>

#define NINT 255
#define HDIM 128
#define BM   16

__device__ __forceinline__ float sp_f(float x) {
    // softplus(x) = log(1 + exp(x)); safe for large |x| in this problem's range
    float e = __expf(x);
    float y = __logf(1.0f + e);
    return (x > 80.0f) ? x : y;
}

__device__ __forceinline__ float tanh_f(float x) {
    float xc = fminf(fmaxf(x, -15.0f), 15.0f);
    float e = __expf(2.0f * xc);
    return (e - 1.0f) * __builtin_amdgcn_rcpf(e + 1.0f);
}

__global__ __launch_bounds__(256, 1)
void cde_persistent(const float* __restrict__ coeffs,
                    const float* __restrict__ W_init, const float* __restrict__ b_init,
                    const float* __restrict__ W1, const float* __restrict__ b1,
                    const float* __restrict__ W2, const float* __restrict__ b2,
                    const float* __restrict__ W3, const float* __restrict__ b3,
                    const float* __restrict__ W_out, const float* __restrict__ b_out,
                    float* __restrict__ out)
{
    // LDS: 2*67584 + 3*8192 + 2048 = 161792 B  (<= 160 KiB)
    __shared__ float W1t[128][132];   // W1 transposed, +4 pad -> bank rotation
    __shared__ float W2t[128][132];
    __shared__ float Zs [16][128];    // stage input z
    __shared__ float H1s[16][128];    // hidden1 / k-partial (chalf 0)
    __shared__ float H2s[16][128];    // hidden2 / k-partial (chalf 1)
    __shared__ float Xds[4][16][8];   // X'(t) for the 4 RK stages

    const int tid     = threadIdx.x;
    const int rowbase = blockIdx.x * BM;

    // ---- one-time: stage W1^T, W2^T into LDS (transpose on the fly)
    for (int idx = tid; idx < 128 * 128; idx += 256) {
        const int k = idx >> 7, j = idx & 127;
        W1t[j][k] = W1[idx];
        W2t[j][k] = W2[idx];
    }

    // roles
    const int jA    = tid & 127;       // mm1/mm2 output column
    const int mbA   = (tid >> 7) * 8;  // mm1/mm2 row group (0 or 8)
    const int hB    = tid & 127;       // mm3 h index
    const int chalf = tid >> 7;        // mm3 c-half (0: c=0..3, 1: c=4..7)
    const int omB   = chalf * 8;       // owner row group

    const float b1r = b1[jA];
    const float b2r = b2[jA];
    float b3r[4];
    {
        const float4 t = *reinterpret_cast<const float4*>(&b3[hB * 8 + chalf * 4]);
        b3r[0] = t.x; b3r[1] = t.y; b3r[2] = t.z; b3r[3] = t.w;
    }

    // ---- z0 = a[:,0] @ W_init + b_init (owners: thread (hB, chalf) owns rows omB..omB+7)
    float zb[8], k1r[8], k2r[8], k3r[8];
    {
        const float bi = b_init[hB];
        #pragma unroll
        for (int m = 0; m < 8; ++m) {
            const float* ap = coeffs + (size_t)(rowbase + omB + m) * (NINT * 32);
            float acc = bi;
            #pragma unroll
            for (int c = 0; c < 8; ++c) acc = fmaf(ap[c], W_init[c * 128 + hB], acc);
            zb[m] = acc;
            Zs[omB + m][hB] = acc;
        }
    }
    __syncthreads();   // covers W staging + z0 + first Xds hazard

    for (int step = 0; step < NINT; ++step) {
        // ---- X'(t) for the 4 stage times of this step
        if (tid < 128) {
            const int m = tid >> 3, c = tid & 7;
            const float* cp = coeffs + (size_t)(rowbase + m) * (NINT * 32);
            float s1;
            if (step == 0) {
                s1 = cp[8 + c];                        // idx 0, frac 0 -> b only
            } else {
                const int i0 = (step - 1) * 32;
                s1 = cp[i0 + 8 + c] + cp[i0 + 16 + c] + cp[i0 + 24 + c]; // frac 1
            }
            const int ik = step * 32;
            const float bB = cp[ik + 8 + c];
            const float tc = cp[ik + 16 + c];
            const float td = cp[ik + 24 + c];
            Xds[0][m][c] = s1;
            Xds[1][m][c] = bB + (tc + td * (1.0f/3.0f)) * (1.0f/3.0f);
            Xds[2][m][c] = bB + (tc + td * (2.0f/3.0f)) * (2.0f/3.0f);
            Xds[3][m][c] = bB + tc + td;
        }
        __syncthreads();

        #pragma unroll 1
        for (int st = 0; st < 4; ++st) {
            // ---- mm1: H1 = softplus(Z @ W1 + b1)
            {
                float o[8];
                #pragma unroll
                for (int m = 0; m < 8; ++m) o[m] = b1r;
                #pragma unroll 4
                for (int kk = 0; kk < 32; ++kk) {
                    const float4 wv = *reinterpret_cast<const float4*>(&W1t[jA][kk * 4]);
                    #pragma unroll
                    for (int m = 0; m < 8; ++m) {
                        const float4 zv = *reinterpret_cast<const float4*>(&Zs[mbA + m][kk * 4]);
                        o[m] = fmaf(zv.x, wv.x, o[m]);
                        o[m] = fmaf(zv.y, wv.y, o[m]);
                        o[m] = fmaf(zv.z, wv.z, o[m]);
                        o[m] = fmaf(zv.w, wv.w, o[m]);
                    }
                }
                #pragma unroll
                for (int m = 0; m < 8; ++m) H1s[mbA + m][jA] = sp_f(o[m]);
            }
            __syncthreads();

            // ---- mm2: H2 = softplus(H1 @ W2 + b2)
            {
                float o[8];
                #pragma unroll
                for (int m = 0; m < 8; ++m) o[m] = b2r;
                #pragma unroll 4
                for (int kk = 0; kk < 32; ++kk) {
                    const float4 wv = *reinterpret_cast<const float4*>(&W2t[jA][kk * 4]);
                    #pragma unroll
                    for (int m = 0; m < 8; ++m) {
                        const float4 zv = *reinterpret_cast<const float4*>(&H1s[mbA + m][kk * 4]);
                        o[m] = fmaf(zv.x, wv.x, o[m]);
                        o[m] = fmaf(zv.y, wv.y, o[m]);
                        o[m] = fmaf(zv.z, wv.z, o[m]);
                        o[m] = fmaf(zv.w, wv.w, o[m]);
                    }
                }
                #pragma unroll
                for (int m = 0; m < 8; ++m) H2s[mbA + m][jA] = sp_f(o[m]);
            }
            __syncthreads();

            // ---- mm3: G = H2 @ W3 (thread (hB,chalf): 16 rows x 4 cols, cols = hB*8+chalf*4+c)
            float acc[16][4];
            #pragma unroll
            for (int m = 0; m < 16; ++m)
                #pragma unroll
                for (int c = 0; c < 4; ++c) acc[m][c] = 0.0f;

            {
                const float* w3base = W3 + hB * 8 + chalf * 4;
                #pragma unroll 2
                for (int kk = 0; kk < 32; ++kk) {
                    float wf[4][4];
                    #pragma unroll
                    for (int i = 0; i < 4; ++i) {
                        const float4 wv = *reinterpret_cast<const float4*>(w3base + (size_t)(kk * 4 + i) * 1024);
                        wf[i][0] = wv.x; wf[i][1] = wv.y; wf[i][2] = wv.z; wf[i][3] = wv.w;
                    }
                    #pragma unroll
                    for (int m = 0; m < 16; ++m) {
                        const float4 hv = *reinterpret_cast<const float4*>(&H2s[m][kk * 4]);
                        const float hf[4] = {hv.x, hv.y, hv.z, hv.w};
                        #pragma unroll
                        for (int i = 0; i < 4; ++i) {
                            #pragma unroll
                            for (int c = 0; c < 4; ++c)
                                acc[m][c] = fmaf(hf[i], wf[i][c], acc[m][c]);
                        }
                    }
                }
            }
            __syncthreads();   // all threads done reading H1s/H2s

            // ---- tanh + contract over this thread's 4 channels; stash partial k
            #pragma unroll
            for (int m = 0; m < 16; ++m) {
                float p = 0.0f;
                #pragma unroll
                for (int c = 0; c < 4; ++c) {
                    const float f = tanh_f(acc[m][c] + b3r[c]);
                    p = fmaf(f, Xds[st][m][chalf * 4 + c], p);
                }
                if (chalf == 0) H1s[m][hB] = p;
                else           H2s[m][hB] = p;
            }
            __syncthreads();

            // ---- owner combines partials, does the RK stage update, writes stage z
            #pragma unroll
            for (int m = 0; m < 8; ++m) {
                const float kv = H1s[omB + m][hB] + H2s[omB + m][hB];
                float znew;
                if (st == 0)      { k1r[m] = kv; znew = zb[m] + kv * (1.0f/3.0f); }
                else if (st == 1) { k2r[m] = kv; znew = zb[m] + kv - k1r[m] * (1.0f/3.0f); }
                else if (st == 2) { k3r[m] = kv; znew = zb[m] + k1r[m] - k2r[m] + kv; }
                else { zb[m] = fmaf(k1r[m] + 3.0f*(k2r[m] + k3r[m]) + kv, 0.125f, zb[m]); znew = zb[m]; }
                Zs[omB + m][hB] = znew;
            }
            __syncthreads();   // Zs ready for next stage / next step
        }
    }

    // ---- epilogue: out = zT @ W_out + b_out  (Zs holds final z)
    if (tid < BM) {
        float acc = b_out[0];
        for (int h = 0; h < 128; ++h) acc = fmaf(Zs[tid][h], W_out[h], acc);
        out[rowbase + tid] = acc;
    }
}

extern "C" void kernel_launch(void* const* d_in, const int* in_sizes, int n_in,
                              void* d_out, int out_size, void* d_ws, size_t ws_size,
                              hipStream_t stream) {
    const float* coeffs = (const float*)d_in[0];
    const float* W_init = (const float*)d_in[1];
    const float* b_init = (const float*)d_in[2];
    const float* W1     = (const float*)d_in[3];
    const float* b1     = (const float*)d_in[4];
    const float* W2     = (const float*)d_in[5];
    const float* b2     = (const float*)d_in[6];
    const float* W3     = (const float*)d_in[7];
    const float* b3     = (const float*)d_in[8];
    const float* W_out  = (const float*)d_in[9];
    const float* b_out  = (const float*)d_in[10];
    float* outp = (float*)d_out;

    hipLaunchKernelGGL(cde_persistent, dim3(4096 / BM), dim3(256), 0, stream,
                       coeffs, W_init, b_init, W1, b1, W2, b2, W3, b3, W_out, b_out, outp);
}

// Round 4
// 6162.476 us; speedup vs baseline: 5.6968x; 5.6968x over previous
//
#include <hip/hip_runtime.h>

#define NINT  255
#define BM    16
#define PITCH 136            // activation row pitch in bf16 elems (128 + 8 pad)

typedef __bf16 bf16x8 __attribute__((ext_vector_type(8)));
typedef float  f32x4  __attribute__((ext_vector_type(4)));

#define MFMA(a, b, c) __builtin_amdgcn_mfma_f32_16x16x32_bf16((a), (b), (c), 0, 0, 0)

__device__ __forceinline__ unsigned short f2b(float f) {
    __bf16 b = (__bf16)f;
    return __builtin_bit_cast(unsigned short, b);
}

__device__ __forceinline__ float sp_f(float x) {
    float e = __expf(x);
    float y = __logf(1.0f + e);
    return (x > 80.0f) ? x : y;
}

__device__ __forceinline__ float tanh_f(float x) {
    float xc = fminf(fmaxf(x, -15.0f), 15.0f);
    float e = __expf(2.0f * xc);
    return (e - 1.0f) * __builtin_amdgcn_rcpf(e + 1.0f);
}

// ---- prep: swizzle W1/W2/W3 into MFMA fragment order (bf16) ----
// frag element e = ((n*4 + t)*64 + l)*8 + i  ->  W[k][col],  k = 32t + (l>>4)*8 + i,
// col = 16n + (l&15).  (B-frag for mm1/mm2; A-frag of W3^T for mm3 — same gather.)
__global__ void prep_frags(const float* __restrict__ W1, const float* __restrict__ W2,
                           const float* __restrict__ W3,
                           unsigned short* __restrict__ W1f, unsigned short* __restrict__ W2f,
                           unsigned short* __restrict__ W3f) {
    const int e = blockIdx.x * 256 + threadIdx.x;   // 0 .. 131071
    const int i = e & 7;
    const int l = (e >> 3) & 63;
    const int t = (e >> 9) & 3;
    const int n = e >> 11;
    const int k = 32 * t + ((l >> 4) & 3) * 8 + i;
    const int c = l & 15;
    if (e < 16384) {
        W1f[e] = f2b(W1[k * 128 + 16 * n + c]);
        W2f[e] = f2b(W2[k * 128 + 16 * n + c]);
    }
    W3f[e] = f2b(W3[k * 1024 + 16 * n + c]);
}

__global__ __launch_bounds__(256, 1)
void cde_mfma(const float* __restrict__ coeffs,
              const float* __restrict__ W_init, const float* __restrict__ b_init,
              const float* __restrict__ b1, const float* __restrict__ b2,
              const float* __restrict__ b3,
              const float* __restrict__ W_out, const float* __restrict__ b_out,
              const unsigned short* __restrict__ w1f, const unsigned short* __restrict__ w2f,
              const unsigned short* __restrict__ w3f,
              float* __restrict__ out)
{
    __shared__ __align__(16) unsigned short W1f_lds[16384];   // 32 KB
    __shared__ __align__(16) unsigned short W2f_lds[16384];   // 32 KB
    __shared__ __align__(16) unsigned short Zs [BM * PITCH];
    __shared__ __align__(16) unsigned short H1s[BM * PITCH];
    __shared__ __align__(16) unsigned short H2s[BM * PITCH];
    __shared__ __align__(16) float Xds[2][4][16][8];          // parity x stage x batch x c
    __shared__ __align__(16) float b1s[128], b2s[128];
    __shared__ __align__(16) float b3s[1024];
    __shared__ __align__(16) float Outp[8][16];

    const int tid     = threadIdx.x;
    const int rowbase = blockIdx.x * BM;
    const int l       = tid & 63;
    const int w       = tid >> 6;          // wave 0..3
    const int batch   = l & 15;
    const int g       = (l >> 4) & 3;
    const int hb      = g >> 1;            // h parity this lane covers in mm3
    const int chB     = 4 * (g & 1);       // c-offset of this lane's 4 channels

    // ---- one-time staging ----
    for (int k4 = tid; k4 < 2048; k4 += 256) {
        ((uint4*)W1f_lds)[k4] = ((const uint4*)w1f)[k4];
        ((uint4*)W2f_lds)[k4] = ((const uint4*)w2f)[k4];
    }
    if (tid < 128) { b1s[tid] = b1[tid]; b2s[tid] = b2[tid]; }
    for (int k = tid; k < 1024; k += 256) b3s[k] = b3[k];

    // ---- z0 = a[:,0] @ W_init + b_init ; lane state: (batch, h = 32w + 2j + hb) ----
    float zb[16], k1r[16], k2r[16], k3r[16];
    {
        const float* ap = coeffs + (size_t)(rowbase + batch) * (NINT * 32);
        float av[8];
        #pragma unroll
        for (int c = 0; c < 8; ++c) av[c] = ap[c];
        #pragma unroll
        for (int j = 0; j < 16; ++j) {
            const int h = 32 * w + 2 * j + hb;
            float z = b_init[h];
            #pragma unroll
            for (int c = 0; c < 8; ++c) z = fmaf(av[c], W_init[c * 128 + h], z);
            zb[j] = z;
            if ((g & 1) == 0) Zs[batch * PITCH + h] = f2b(z);
        }
    }
    __syncthreads();

    const bf16x8* wf1 = (const bf16x8*)W1f_lds;
    const bf16x8* wf2 = (const bf16x8*)W2f_lds;
    const bf16x8* w3v = (const bf16x8*)w3f;
    const int n0 = 2 * w, n1 = 2 * w + 1;
    const int cA = batch;                  // mm1/mm2 output col within tile
    const int koff = g * 8;                // k-chunk offset within A/B frag rows

    #pragma unroll 1
    for (int step = 0; step < NINT; ++step) {
        const int par = step & 1;
        if (tid < 128) {
            const int m = tid >> 3, c = tid & 7;
            const float* cp = coeffs + (size_t)(rowbase + m) * (NINT * 32);
            float s1;
            if (step == 0) s1 = cp[8 + c];
            else {
                const int i0 = (step - 1) * 32;
                s1 = cp[i0 + 8 + c] + cp[i0 + 16 + c] + cp[i0 + 24 + c];
            }
            const int ik = step * 32;
            const float bB = cp[ik + 8 + c];
            const float tc = cp[ik + 16 + c];
            const float td = cp[ik + 24 + c];
            Xds[par][0][m][c] = s1;
            Xds[par][1][m][c] = bB + (tc + td * (1.0f/3.0f)) * (1.0f/3.0f);
            Xds[par][2][m][c] = bB + (tc + td * (2.0f/3.0f)) * (2.0f/3.0f);
            Xds[par][3][m][c] = bB + tc + td;
        }

        #pragma unroll 1
        for (int st = 0; st < 4; ++st) {
            // ================= mm1: H1 = softplus(Z @ W1 + b1) =================
            {
                bf16x8 a[4];
                #pragma unroll
                for (int t = 0; t < 4; ++t)
                    a[t] = *(const bf16x8*)(Zs + batch * PITCH + t * 32 + koff);
                const float bi0 = b1s[16 * n0 + cA], bi1 = b1s[16 * n1 + cA];
                f32x4 acc0 = {bi0, bi0, bi0, bi0};
                f32x4 acc1 = {bi1, bi1, bi1, bi1};
                #pragma unroll
                for (int t = 0; t < 4; ++t) {
                    acc0 = MFMA(a[t], wf1[(n0 * 4 + t) * 64 + l], acc0);
                    acc1 = MFMA(a[t], wf1[(n1 * 4 + t) * 64 + l], acc1);
                }
                #pragma unroll
                for (int i = 0; i < 4; ++i) {
                    H1s[(g * 4 + i) * PITCH + 16 * n0 + cA] = f2b(sp_f(acc0[i]));
                    H1s[(g * 4 + i) * PITCH + 16 * n1 + cA] = f2b(sp_f(acc1[i]));
                }
            }
            __syncthreads();

            // ================= mm2: H2 = softplus(H1 @ W2 + b2) =================
            {
                bf16x8 a[4];
                #pragma unroll
                for (int t = 0; t < 4; ++t)
                    a[t] = *(const bf16x8*)(H1s + batch * PITCH + t * 32 + koff);
                const float bi0 = b2s[16 * n0 + cA], bi1 = b2s[16 * n1 + cA];
                f32x4 acc0 = {bi0, bi0, bi0, bi0};
                f32x4 acc1 = {bi1, bi1, bi1, bi1};
                #pragma unroll
                for (int t = 0; t < 4; ++t) {
                    acc0 = MFMA(a[t], wf2[(n0 * 4 + t) * 64 + l], acc0);
                    acc1 = MFMA(a[t], wf2[(n1 * 4 + t) * 64 + l], acc1);
                }
                #pragma unroll
                for (int i = 0; i < 4; ++i) {
                    H2s[(g * 4 + i) * PITCH + 16 * n0 + cA] = f2b(sp_f(acc0[i]));
                    H2s[(g * 4 + i) * PITCH + 16 * n1 + cA] = f2b(sp_f(acc1[i]));
                }
            }
            __syncthreads();

            // ===== mm3 (transposed): G^T tile rows = W3 cols, cols = batch =====
            {
                bf16x8 bfr[4];
                #pragma unroll
                for (int t = 0; t < 4; ++t)
                    bfr[t] = *(const bf16x8*)(H2s + batch * PITCH + t * 32 + koff);

                f32x4 acc[16];
                #pragma unroll
                for (int j = 0; j < 16; ++j)
                    acc[j] = *(const f32x4*)&b3s[16 * (16 * w + j) + 4 * g];

                bf16x8 aw[16][4];
                #pragma unroll
                for (int jj = 0; jj < 4; ++jj)
                    #pragma unroll
                    for (int t = 0; t < 4; ++t)
                        aw[jj][t] = w3v[((16 * w + jj) * 4 + t) * 64 + l];

                #pragma unroll
                for (int j = 0; j < 16; ++j) {
                    if (j < 12) {
                        #pragma unroll
                        for (int t = 0; t < 4; ++t)
                            aw[j + 4][t] = w3v[((16 * w + j + 4) * 4 + t) * 64 + l];
                    }
                    #pragma unroll
                    for (int t = 0; t < 4; ++t)
                        acc[j] = MFMA(aw[j][t], bfr[t], acc[j]);
                }

                // ---- tanh + contract over 4 lane-local channels + pair-sum ----
                const f32x4 xdv = *(const f32x4*)&Xds[par][st][batch][chB];
                #pragma unroll
                for (int j = 0; j < 16; ++j) {
                    float p = 0.0f;
                    #pragma unroll
                    for (int i = 0; i < 4; ++i)
                        p = fmaf(tanh_f(acc[j][i]), xdv[i], p);
                    p += __shfl_xor(p, 16, 64);   // combine the two c-halves
                    float znew;
                    if (st == 0)      { k1r[j] = p; znew = zb[j] + p * (1.0f/3.0f); }
                    else if (st == 1) { k2r[j] = p; znew = zb[j] + p - k1r[j] * (1.0f/3.0f); }
                    else if (st == 2) { k3r[j] = p; znew = zb[j] + k1r[j] - k2r[j] + p; }
                    else { zb[j] = fmaf(k1r[j] + 3.0f * (k2r[j] + k3r[j]) + p, 0.125f, zb[j]); znew = zb[j]; }
                    if ((g & 1) == 0)
                        Zs[batch * PITCH + 32 * w + 2 * j + hb] = f2b(znew);
                }
            }
            __syncthreads();
        }
    }

    // ---- epilogue: out = zT @ W_out + b_out ----
    if ((g & 1) == 0) {
        float prt = 0.0f;
        #pragma unroll
        for (int j = 0; j < 16; ++j)
            prt = fmaf(zb[j], W_out[32 * w + 2 * j + hb], prt);
        Outp[w * 2 + hb][batch] = prt;
    }
    __syncthreads();
    if (tid < 16) {
        float s = b_out[0];
        #pragma unroll
        for (int p = 0; p < 8; ++p) s += Outp[p][tid];
        out[rowbase + tid] = s;
    }
}

extern "C" void kernel_launch(void* const* d_in, const int* in_sizes, int n_in,
                              void* d_out, int out_size, void* d_ws, size_t ws_size,
                              hipStream_t stream) {
    const float* coeffs = (const float*)d_in[0];
    const float* W_init = (const float*)d_in[1];
    const float* b_init = (const float*)d_in[2];
    const float* W1     = (const float*)d_in[3];
    const float* b1     = (const float*)d_in[4];
    const float* W2     = (const float*)d_in[5];
    const float* b2     = (const float*)d_in[6];
    const float* W3     = (const float*)d_in[7];
    const float* b3     = (const float*)d_in[8];
    const float* W_out  = (const float*)d_in[9];
    const float* b_out  = (const float*)d_in[10];
    float* outp = (float*)d_out;

    unsigned short* w1f = (unsigned short*)d_ws;            // 32 KB
    unsigned short* w2f = w1f + 16384;                      // 32 KB
    unsigned short* w3f = w2f + 16384;                      // 256 KB

    hipLaunchKernelGGL(prep_frags, dim3(512), dim3(256), 0, stream, W1, W2, W3, w1f, w2f, w3f);
    hipLaunchKernelGGL(cde_mfma, dim3(4096 / BM), dim3(256), 0, stream,
                       coeffs, W_init, b_init, b1, b2, b3, W_out, b_out,
                       w1f, w2f, w3f, outp);
}

// Round 5
// 3012.861 us; speedup vs baseline: 11.6521x; 2.0454x over previous
//
#include <hip/hip_runtime.h>

#define NINT  255
#define BM    16
#define PITCH 136            // activation row pitch in bf16 elems (128 + 8 pad)

typedef __bf16 bf16x8 __attribute__((ext_vector_type(8)));
typedef float  f32x4  __attribute__((ext_vector_type(4)));

#define MFMA(a, b, c) __builtin_amdgcn_mfma_f32_16x16x32_bf16((a), (b), (c), 0, 0, 0)

__device__ __forceinline__ unsigned short f2b(float f) {
    __bf16 b = (__bf16)f;
    return __builtin_bit_cast(unsigned short, b);
}

// softplus = ln2 * log2(1 + 2^(x*log2e)); guard only the 2^x overflow region
__device__ __forceinline__ float sp_f(float x) {
    float e = __builtin_amdgcn_exp2f(x * 1.4426950408889634f);
    float y = __builtin_amdgcn_logf(1.0f + e) * 0.6931471805599453f;
    return (x > 80.0f) ? x : y;
}

// tanh = 1 - 2/(2^(2x*log2e) + 1); saturates correctly at +-inf via v_exp/v_rcp
__device__ __forceinline__ float tanh_f(float x) {
    float e = __builtin_amdgcn_exp2f(x * 2.8853900817779268f);
    float r = __builtin_amdgcn_rcpf(e + 1.0f);
    return fmaf(-2.0f, r, 1.0f);
}

// ---- prep: swizzle W1/W2/W3 into MFMA fragment order (bf16) ----
// frag element e = ((n*4 + t)*64 + l)*8 + i  ->  W[k][col],  k = 32t + (l>>4)*8 + i,
// col = 16n + (l&15).
__global__ void prep_frags(const float* __restrict__ W1, const float* __restrict__ W2,
                           const float* __restrict__ W3,
                           unsigned short* __restrict__ W1f, unsigned short* __restrict__ W2f,
                           unsigned short* __restrict__ W3f) {
    const int e = blockIdx.x * 256 + threadIdx.x;   // 0 .. 131071
    const int i = e & 7;
    const int l = (e >> 3) & 63;
    const int t = (e >> 9) & 3;
    const int n = e >> 11;
    const int k = 32 * t + ((l >> 4) & 3) * 8 + i;
    const int c = l & 15;
    if (e < 16384) {
        W1f[e] = f2b(W1[k * 128 + 16 * n + c]);
        W2f[e] = f2b(W2[k * 128 + 16 * n + c]);
    }
    W3f[e] = f2b(W3[k * 1024 + 16 * n + c]);
}

__global__ __launch_bounds__(512, 2)
void cde_mfma(const float* __restrict__ coeffs,
              const float* __restrict__ W_init, const float* __restrict__ b_init,
              const float* __restrict__ b1, const float* __restrict__ b2,
              const float* __restrict__ b3,
              const float* __restrict__ W_out, const float* __restrict__ b_out,
              const unsigned short* __restrict__ w1f, const unsigned short* __restrict__ w2f,
              const unsigned short* __restrict__ w3f,
              float* __restrict__ out)
{
    // LDS: 131072 + 3*4352 + 4096 + 4096 + 1024 = 153344 B (<= 160 KiB)
    __shared__ __align__(16) unsigned short W3r_lds[65536];   // 128 KB: W3 tiles jg=32..63
    __shared__ __align__(16) unsigned short Zs [BM * PITCH];
    __shared__ __align__(16) unsigned short H1s[BM * PITCH];
    __shared__ __align__(16) unsigned short H2s[BM * PITCH];
    __shared__ __align__(16) float Xds[2][4][16][8];          // parity x stage x batch x c
    __shared__ __align__(16) float b3s[1024];
    __shared__ __align__(16) float Outp[16][16];

    const int tid     = threadIdx.x;        // 0..511
    const int rowbase = blockIdx.x * BM;
    const int l       = tid & 63;
    const int w       = tid >> 6;           // wave 0..7
    const int batch   = l & 15;
    const int g       = (l >> 4) & 3;
    const int hb      = g >> 1;             // which of the tile's 2 h values
    const int chB     = 4 * (g & 1);        // c-offset of this lane's 4 channels
    const int koff    = g * 8;

    // ---- one-time: W3 tiles 32..63 -> LDS (128 KB) ----
    for (int k4 = tid; k4 < 8192; k4 += 512)
        ((uint4*)W3r_lds)[k4] = ((const uint4*)(w3f + 32 * 2048))[k4];
    for (int k = tid; k < 1024; k += 512) b3s[k] = b3[k];

    // ---- per-wave weight fragments in registers ----
    const bf16x8* w1v = (const bf16x8*)w1f;
    const bf16x8* w2v = (const bf16x8*)w2f;
    const bf16x8* w3v = (const bf16x8*)w3f;
    bf16x8 w1r[4], w2r[4], w3g[4][4];
    #pragma unroll
    for (int t = 0; t < 4; ++t) {
        w1r[t] = w1v[(w * 4 + t) * 64 + l];
        w2r[t] = w2v[(w * 4 + t) * 64 + l];
    }
    #pragma unroll
    for (int jl = 0; jl < 4; ++jl)
        #pragma unroll
        for (int t = 0; t < 4; ++t)
            w3g[jl][t] = w3v[((8 * jl + w) * 4 + t) * 64 + l];

    const float b1r = b1[16 * w + batch];
    const float b2r = b2[16 * w + batch];

    // ---- z0 = a[:,0] @ W_init + b_init ; lane state h = 16*jl + 2*w + hb ----
    float zb[8], k1r[8], k2r[8], k3r[8];
    {
        const float* ap = coeffs + (size_t)(rowbase + batch) * (NINT * 32);
        float av[8];
        #pragma unroll
        for (int c = 0; c < 8; ++c) av[c] = ap[c];
        #pragma unroll
        for (int jl = 0; jl < 8; ++jl) {
            const int h = 16 * jl + 2 * w + hb;
            float z = b_init[h];
            #pragma unroll
            for (int c = 0; c < 8; ++c) z = fmaf(av[c], W_init[c * 128 + h], z);
            zb[jl] = z;
            if ((g & 1) == 0) Zs[batch * PITCH + h] = f2b(z);
        }
    }
    __syncthreads();

    const bf16x8* w3rv = (const bf16x8*)W3r_lds;

    #pragma unroll 1
    for (int step = 0; step < NINT; ++step) {
        const int par = step & 1;
        if (tid < 128) {
            const int m = tid >> 3, c = tid & 7;
            const float* cp = coeffs + (size_t)(rowbase + m) * (NINT * 32);
            float s1;
            if (step == 0) s1 = cp[8 + c];
            else {
                const int i0 = (step - 1) * 32;
                s1 = cp[i0 + 8 + c] + cp[i0 + 16 + c] + cp[i0 + 24 + c];
            }
            const int ik = step * 32;
            const float bB = cp[ik + 8 + c];
            const float tc = cp[ik + 16 + c];
            const float td = cp[ik + 24 + c];
            Xds[par][0][m][c] = s1;
            Xds[par][1][m][c] = bB + (tc + td * (1.0f/3.0f)) * (1.0f/3.0f);
            Xds[par][2][m][c] = bB + (tc + td * (2.0f/3.0f)) * (2.0f/3.0f);
            Xds[par][3][m][c] = bB + tc + td;
        }

        #pragma unroll 1
        for (int st = 0; st < 4; ++st) {
            // ============ mm1: H1 = softplus(Z @ W1 + b1), 1 col-tile/wave ============
            {
                bf16x8 a[4];
                #pragma unroll
                for (int t = 0; t < 4; ++t)
                    a[t] = *(const bf16x8*)(Zs + batch * PITCH + t * 32 + koff);
                f32x4 acc0 = {b1r, b1r, b1r, b1r};
                #pragma unroll
                for (int t = 0; t < 4; ++t) acc0 = MFMA(a[t], w1r[t], acc0);
                #pragma unroll
                for (int i = 0; i < 4; ++i)
                    H1s[(g * 4 + i) * PITCH + 16 * w + batch] = f2b(sp_f(acc0[i]));
            }
            __syncthreads();

            // ============ mm2: H2 = softplus(H1 @ W2 + b2) ============
            {
                bf16x8 a[4];
                #pragma unroll
                for (int t = 0; t < 4; ++t)
                    a[t] = *(const bf16x8*)(H1s + batch * PITCH + t * 32 + koff);
                f32x4 acc0 = {b2r, b2r, b2r, b2r};
                #pragma unroll
                for (int t = 0; t < 4; ++t) acc0 = MFMA(a[t], w2r[t], acc0);
                #pragma unroll
                for (int i = 0; i < 4; ++i)
                    H2s[(g * 4 + i) * PITCH + 16 * w + batch] = f2b(sp_f(acc0[i]));
            }
            __syncthreads();

            // ==== mm3 (transposed): 8 W3-col tiles/wave, all weights resident ====
            {
                bf16x8 bfr[4];
                #pragma unroll
                for (int t = 0; t < 4; ++t)
                    bfr[t] = *(const bf16x8*)(H2s + batch * PITCH + t * 32 + koff);

                f32x4 acc[8];
                #pragma unroll
                for (int jl = 0; jl < 8; ++jl)
                    acc[jl] = *(const f32x4*)&b3s[16 * (8 * jl + w) + 4 * g];

                #pragma unroll
                for (int jl = 0; jl < 4; ++jl)
                    #pragma unroll
                    for (int t = 0; t < 4; ++t)
                        acc[jl] = MFMA(w3g[jl][t], bfr[t], acc[jl]);

                #pragma unroll
                for (int jl = 4; jl < 8; ++jl)
                    #pragma unroll
                    for (int t = 0; t < 4; ++t)
                        acc[jl] = MFMA(w3rv[(((jl - 4) * 8 + w) * 4 + t) * 64 + l], bfr[t], acc[jl]);

                // ---- tanh + contract over 4 lane-local channels + pair-sum ----
                const f32x4 xdv = *(const f32x4*)&Xds[par][st][batch][chB];
                #pragma unroll
                for (int jl = 0; jl < 8; ++jl) {
                    float p = 0.0f;
                    #pragma unroll
                    for (int i = 0; i < 4; ++i)
                        p = fmaf(tanh_f(acc[jl][i]), xdv[i], p);
                    p += __shfl_xor(p, 16, 64);   // combine the two c-halves
                    float znew;
                    if (st == 0)      { k1r[jl] = p; znew = zb[jl] + p * (1.0f/3.0f); }
                    else if (st == 1) { k2r[jl] = p; znew = zb[jl] + p - k1r[jl] * (1.0f/3.0f); }
                    else if (st == 2) { k3r[jl] = p; znew = zb[jl] + k1r[jl] - k2r[jl] + p; }
                    else { zb[jl] = fmaf(k1r[jl] + 3.0f * (k2r[jl] + k3r[jl]) + p, 0.125f, zb[jl]); znew = zb[jl]; }
                    if ((g & 1) == 0)
                        Zs[batch * PITCH + 16 * jl + 2 * w + hb] = f2b(znew);
                }
            }
            __syncthreads();
        }
    }

    // ---- epilogue: out = zT @ W_out + b_out ----
    if ((g & 1) == 0) {
        float prt = 0.0f;
        #pragma unroll
        for (int jl = 0; jl < 8; ++jl)
            prt = fmaf(zb[jl], W_out[16 * jl + 2 * w + hb], prt);
        Outp[2 * w + hb][batch] = prt;
    }
    __syncthreads();
    if (tid < 16) {
        float s = b_out[0];
        #pragma unroll
        for (int p = 0; p < 16; ++p) s += Outp[p][tid];
        out[rowbase + tid] = s;
    }
}

extern "C" void kernel_launch(void* const* d_in, const int* in_sizes, int n_in,
                              void* d_out, int out_size, void* d_ws, size_t ws_size,
                              hipStream_t stream) {
    const float* coeffs = (const float*)d_in[0];
    const float* W_init = (const float*)d_in[1];
    const float* b_init = (const float*)d_in[2];
    const float* W1     = (const float*)d_in[3];
    const float* b1     = (const float*)d_in[4];
    const float* W2     = (const float*)d_in[5];
    const float* b2     = (const float*)d_in[6];
    const float* W3     = (const float*)d_in[7];
    const float* b3     = (const float*)d_in[8];
    const float* W_out  = (const float*)d_in[9];
    const float* b_out  = (const float*)d_in[10];
    float* outp = (float*)d_out;

    unsigned short* w1f = (unsigned short*)d_ws;            // 32 KB
    unsigned short* w2f = w1f + 16384;                      // 32 KB
    unsigned short* w3f = w2f + 16384;                      // 256 KB

    hipLaunchKernelGGL(prep_frags, dim3(512), dim3(256), 0, stream, W1, W2, W3, w1f, w2f, w3f);
    hipLaunchKernelGGL(cde_mfma, dim3(4096 / BM), dim3(512), 0, stream,
                       coeffs, W_init, b_init, b1, b2, b3, W_out, b_out,
                       w1f, w2f, w3f, outp);
}

// Round 6
// 2552.949 us; speedup vs baseline: 13.7513x; 1.1801x over previous
//
#include <hip/hip_runtime.h>

#define NINT  255
#define BM    16
#define PITCH 136            // activation row pitch in bf16 elems (128 + 8 pad)

typedef __bf16 bf16x8 __attribute__((ext_vector_type(8)));
typedef float  f32x4  __attribute__((ext_vector_type(4)));

#define MFMA(a, b, c) __builtin_amdgcn_mfma_f32_16x16x32_bf16((a), (b), (c), 0, 0, 0)

__device__ __forceinline__ unsigned short f2b(float f) {
    __bf16 b = (__bf16)f;
    return __builtin_bit_cast(unsigned short, b);
}

// softplus = ln2 * log2(1 + 2^(x*log2e)); guard only the overflow region
__device__ __forceinline__ float sp_f(float x) {
    float e = __builtin_amdgcn_exp2f(x * 1.4426950408889634f);
    float y = __builtin_amdgcn_logf(1.0f + e) * 0.6931471805599453f;
    return (x > 80.0f) ? x : y;
}

// tanh = 1 - 2/(2^(2x*log2e) + 1); saturates correctly at +-inf via v_exp/v_rcp
__device__ __forceinline__ float tanh_f(float x) {
    float e = __builtin_amdgcn_exp2f(x * 2.8853900817779268f);
    float r = __builtin_amdgcn_rcpf(e + 1.0f);
    return fmaf(-2.0f, r, 1.0f);
}

// ---- prep: swizzle W1/W2/W3 into MFMA fragment order (bf16) ----
// frag element e = ((n*4 + t)*64 + l)*8 + i  ->  W[k][col],  k = 32t + (l>>4)*8 + i,
// col = 16n + (l&15).
__global__ void prep_frags(const float* __restrict__ W1, const float* __restrict__ W2,
                           const float* __restrict__ W3,
                           unsigned short* __restrict__ W1f, unsigned short* __restrict__ W2f,
                           unsigned short* __restrict__ W3f) {
    const int e = blockIdx.x * 256 + threadIdx.x;   // 0 .. 131071
    const int i = e & 7;
    const int l = (e >> 3) & 63;
    const int t = (e >> 9) & 3;
    const int n = e >> 11;
    const int k = 32 * t + ((l >> 4) & 3) * 8 + i;
    const int c = l & 15;
    if (e < 16384) {
        W1f[e] = f2b(W1[k * 128 + 16 * n + c]);
        W2f[e] = f2b(W2[k * 128 + 16 * n + c]);
    }
    W3f[e] = f2b(W3[k * 1024 + 16 * n + c]);
}

// One RK stage: mm1 -> mm2 -> mm3(+tanh+contract+RK update). ST is a literal.
#define STAGE_BODY(ST, XD)                                                       \
{                                                                                \
    bf16x8 a0[4];                                                                \
    _Pragma("unroll")                                                            \
    for (int t = 0; t < 4; ++t)                                                  \
        a0[t] = *(const bf16x8*)(Zs + batch * PITCH + t * 32 + koff);            \
    f32x4 h1 = {b1r, b1r, b1r, b1r};                                             \
    _Pragma("unroll")                                                            \
    for (int t = 0; t < 4; ++t) h1 = MFMA(a0[t], w1r[t], h1);                    \
    _Pragma("unroll")                                                            \
    for (int i = 0; i < 4; ++i)                                                  \
        H1s[(g * 4 + i) * PITCH + 16 * w + batch] = f2b(sp_f(h1[i]));            \
    __syncthreads();                                                             \
    bf16x8 a1[4];                                                                \
    _Pragma("unroll")                                                            \
    for (int t = 0; t < 4; ++t)                                                  \
        a1[t] = *(const bf16x8*)(H1s + batch * PITCH + t * 32 + koff);           \
    f32x4 h2 = {b2r, b2r, b2r, b2r};                                             \
    _Pragma("unroll")                                                            \
    for (int t = 0; t < 4; ++t) h2 = MFMA(a1[t], w2r[t], h2);                    \
    _Pragma("unroll")                                                            \
    for (int i = 0; i < 4; ++i)                                                  \
        H2s[(g * 4 + i) * PITCH + 16 * w + batch] = f2b(sp_f(h2[i]));            \
    __syncthreads();                                                             \
    bf16x8 bfr[4];                                                               \
    _Pragma("unroll")                                                            \
    for (int t = 0; t < 4; ++t)                                                  \
        bfr[t] = *(const bf16x8*)(H2s + batch * PITCH + t * 32 + koff);          \
    f32x4 acc[8];                                                                \
    _Pragma("unroll")                                                            \
    for (int jl = 0; jl < 4; ++jl) {                                             \
        acc[jl] = MFMA(w3g[jl][0], bfr[0], b3r8[jl]);                            \
        _Pragma("unroll")                                                        \
        for (int t = 1; t < 4; ++t) acc[jl] = MFMA(w3g[jl][t], bfr[t], acc[jl]); \
    }                                                                            \
    _Pragma("unroll")                                                            \
    for (int jl = 4; jl < 8; ++jl) {                                             \
        acc[jl] = MFMA(w3rv[(((jl - 4) * 8 + w) * 4 + 0) * 64 + l], bfr[0], b3r8[jl]); \
        _Pragma("unroll")                                                        \
        for (int t = 1; t < 4; ++t)                                              \
            acc[jl] = MFMA(w3rv[(((jl - 4) * 8 + w) * 4 + t) * 64 + l], bfr[t], acc[jl]); \
    }                                                                            \
    _Pragma("unroll")                                                            \
    for (int jl = 0; jl < 8; ++jl) {                                             \
        float p = 0.0f;                                                          \
        _Pragma("unroll")                                                        \
        for (int i = 0; i < 4; ++i) p = fmaf(tanh_f(acc[jl][i]), (XD)[i], p);    \
        p += __shfl_xor(p, 16, 64);                                              \
        float znew;                                                              \
        if (ST == 0)      { k1r[jl] = p; znew = zb[jl] + p * (1.0f/3.0f); }      \
        else if (ST == 1) { k2r[jl] = p; znew = zb[jl] + p - k1r[jl] * (1.0f/3.0f); } \
        else if (ST == 2) { k3r[jl] = p; znew = zb[jl] + k1r[jl] - k2r[jl] + p; } \
        else { zb[jl] = fmaf(k1r[jl] + 3.0f*(k2r[jl] + k3r[jl]) + p, 0.125f, zb[jl]); znew = zb[jl]; } \
        if ((g & 1) == 0)                                                        \
            Zs[batch * PITCH + 16 * jl + 2 * w + hb] = f2b(znew);                \
    }                                                                            \
    __syncthreads();                                                             \
}

__global__ __launch_bounds__(512, 2)
void cde_mfma(const float* __restrict__ coeffs,
              const float* __restrict__ W_init, const float* __restrict__ b_init,
              const float* __restrict__ b1, const float* __restrict__ b2,
              const float* __restrict__ b3,
              const float* __restrict__ W_out, const float* __restrict__ b_out,
              const unsigned short* __restrict__ w1f, const unsigned short* __restrict__ w2f,
              const unsigned short* __restrict__ w3f,
              float* __restrict__ out)
{
    // LDS: 131072 + 3*4352 + 1024 = 145152 B
    __shared__ __align__(16) unsigned short W3r_lds[65536];   // 128 KB: W3 tiles 32..63
    __shared__ __align__(16) unsigned short Zs [BM * PITCH];
    __shared__ __align__(16) unsigned short H1s[BM * PITCH];
    __shared__ __align__(16) unsigned short H2s[BM * PITCH];
    __shared__ __align__(16) float Outp[16][16];

    const int tid     = threadIdx.x;        // 0..511
    const int rowbase = blockIdx.x * BM;
    const int l       = tid & 63;
    const int w       = tid >> 6;           // wave 0..7
    const int batch   = l & 15;
    const int g       = (l >> 4) & 3;
    const int hb      = g >> 1;             // which of the tile's 2 h values
    const int chB     = 4 * (g & 1);        // c-offset of this lane's 4 channels
    const int koff    = g * 8;

    // ---- one-time: W3 tiles 32..63 -> LDS (128 KB) ----
    for (int k4 = tid; k4 < 8192; k4 += 512)
        ((uint4*)W3r_lds)[k4] = ((const uint4*)(w3f + 32 * 2048))[k4];

    // ---- per-wave weight fragments + biases in registers ----
    const bf16x8* w1v = (const bf16x8*)w1f;
    const bf16x8* w2v = (const bf16x8*)w2f;
    const bf16x8* w3v = (const bf16x8*)w3f;
    bf16x8 w1r[4], w2r[4], w3g[4][4];
    #pragma unroll
    for (int t = 0; t < 4; ++t) {
        w1r[t] = w1v[(w * 4 + t) * 64 + l];
        w2r[t] = w2v[(w * 4 + t) * 64 + l];
    }
    #pragma unroll
    for (int jl = 0; jl < 4; ++jl)
        #pragma unroll
        for (int t = 0; t < 4; ++t)
            w3g[jl][t] = w3v[((8 * jl + w) * 4 + t) * 64 + l];

    const float b1r = b1[16 * w + batch];
    const float b2r = b2[16 * w + batch];
    f32x4 b3r8[8];
    #pragma unroll
    for (int jl = 0; jl < 8; ++jl)
        b3r8[jl] = *(const f32x4*)&b3[16 * (8 * jl + w) + 4 * g];

    // ---- z0 = a[:,0] @ W_init + b_init ; lane state h = 16*jl + 2*w + hb ----
    float zb[8], k1r[8], k2r[8], k3r[8];
    {
        const float* ap = coeffs + (size_t)(rowbase + batch) * (NINT * 32);
        float av[8];
        #pragma unroll
        for (int c = 0; c < 8; ++c) av[c] = ap[c];
        #pragma unroll
        for (int jl = 0; jl < 8; ++jl) {
            const int h = 16 * jl + 2 * w + hb;
            float z = b_init[h];
            #pragma unroll
            for (int c = 0; c < 8; ++c) z = fmaf(av[c], W_init[c * 128 + h], z);
            zb[jl] = z;
            if ((g & 1) == 0) Zs[batch * PITCH + h] = f2b(z);
        }
    }

    // ---- X'(t) register state: this lane's 4 channels chB..chB+3 ----
    const float* cpx = coeffs + (size_t)(rowbase + batch) * (NINT * 32) + chB;
    f32x4 bB  = *(const f32x4*)(cpx + 8);
    f32x4 tcv = *(const f32x4*)(cpx + 16);
    f32x4 tdv = *(const f32x4*)(cpx + 24);
    f32x4 xd0 = bB;                       // X'(0): interval 0, frac 0 -> b only

    const bf16x8* w3rv = (const bf16x8*)W3r_lds;
    __syncthreads();

    #pragma unroll 1
    for (int step = 0; step < NINT; ++step) {
        // prefetch next step's coeffs (clamped; hidden under stage 0)
        const int nxt = (step + 1 < NINT) ? step + 1 : NINT - 1;
        const float* cn = cpx + nxt * 32;
        const f32x4 nbB = *(const f32x4*)(cn + 8);
        const f32x4 ntc = *(const f32x4*)(cn + 16);
        const f32x4 ntd = *(const f32x4*)(cn + 24);

        STAGE_BODY(0, xd0)

        f32x4 xd1, xd2, xd3;
        #pragma unroll
        for (int i = 0; i < 4; ++i) {
            xd1[i] = bB[i] + (tcv[i] + tdv[i] * (1.0f/3.0f)) * (1.0f/3.0f);
            xd2[i] = bB[i] + (tcv[i] + tdv[i] * (2.0f/3.0f)) * (2.0f/3.0f);
            xd3[i] = bB[i] + tcv[i] + tdv[i];
        }

        STAGE_BODY(1, xd1)
        STAGE_BODY(2, xd2)
        STAGE_BODY(3, xd3)

        xd0 = xd3;                        // X' at frac 1 == next step's stage-0 X'
        bB = nbB; tcv = ntc; tdv = ntd;
    }

    // ---- epilogue: out = zT @ W_out + b_out ----
    if ((g & 1) == 0) {
        float prt = 0.0f;
        #pragma unroll
        for (int jl = 0; jl < 8; ++jl)
            prt = fmaf(zb[jl], W_out[16 * jl + 2 * w + hb], prt);
        Outp[2 * w + hb][batch] = prt;
    }
    __syncthreads();
    if (tid < 16) {
        float s = b_out[0];
        #pragma unroll
        for (int p = 0; p < 16; ++p) s += Outp[p][tid];
        out[rowbase + tid] = s;
    }
}

extern "C" void kernel_launch(void* const* d_in, const int* in_sizes, int n_in,
                              void* d_out, int out_size, void* d_ws, size_t ws_size,
                              hipStream_t stream) {
    const float* coeffs = (const float*)d_in[0];
    const float* W_init = (const float*)d_in[1];
    const float* b_init = (const float*)d_in[2];
    const float* W1     = (const float*)d_in[3];
    const float* b1     = (const float*)d_in[4];
    const float* W2     = (const float*)d_in[5];
    const float* b2     = (const float*)d_in[6];
    const float* W3     = (const float*)d_in[7];
    const float* b3     = (const float*)d_in[8];
    const float* W_out  = (const float*)d_in[9];
    const float* b_out  = (const float*)d_in[10];
    float* outp = (float*)d_out;

    unsigned short* w1f = (unsigned short*)d_ws;            // 32 KB
    unsigned short* w2f = w1f + 16384;                      // 32 KB
    unsigned short* w3f = w2f + 16384;                      // 256 KB

    hipLaunchKernelGGL(prep_frags, dim3(512), dim3(256), 0, stream, W1, W2, W3, w1f, w2f, w3f);
    hipLaunchKernelGGL(cde_mfma, dim3(4096 / BM), dim3(512), 0, stream,
                       coeffs, W_init, b_init, b1, b2, b3, W_out, b_out,
                       w1f, w2f, w3f, outp);
}